// Round 18
// baseline (132.505 us; speedup 1.0000x reference)
//
#include <hip/hip_runtime.h>
#include <math.h>

#define NOSC 2048
#define NB 16
#define DT 0.1f
#define M_TOT (NB * NOSC)    // 32768
#define KTP 2056             // padded LDS K row

typedef __attribute__((ext_vector_type(8))) short bf16x8;
typedef __attribute__((ext_vector_type(4))) float f32x4;

__device__ __forceinline__ unsigned short f2bf(float x) {
    unsigned int u = __float_as_uint(x);
    u += 0x7FFFu + ((u >> 16) & 1u);          // round-to-nearest-even
    return (unsigned short)(u >> 16);
}

// Per-half fragment-tiled R layout. Half h (batches h*8..h*8+7) owns a
// 16x2048 table at R + h*M_TOT: row c16 = bs for sin, 8+bs for cos.
// idx(c16, j) = (j>>3)*128 + c16*8 + (j&7).
// Wave w (k-sixteenth, 128 j): A-fragment chunk k is CONTIGUOUS at
// [w*2048 + k*512 + lane*8 .. +8) shorts  (verified: (w*16+k*4+(l>>4))*128
// + (l&15)*8 + e == w*2048 + k*512 + l*8 + e).

// ws layout: Kb[2048][2048] bf16 (8 MB) | RA (64K shorts) | RB | accum[32] f32 | ticket

// ---------- init: copy theta, build tiled R0, zero accum/ticket ----------
__global__ void init_kernel(const float* __restrict__ th_in,
                            float* __restrict__ th,
                            unsigned short* __restrict__ R0,
                            float* __restrict__ accum,
                            unsigned int* __restrict__ ticket) {
    const int idx = blockIdx.x * 256 + threadIdx.x;   // 0..8191
    const int o4 = idx * 4;
    float4 v = *reinterpret_cast<const float4*>(th_in + o4);
    *reinterpret_cast<float4*>(th + o4) = v;
    const int b = o4 >> 11;
    const int j = o4 & (NOSC - 1);
    const int h = b >> 3, bs = b & 7;
    float s0, c0, s1, c1, s2, c2, s3, c3;
    sincosf(v.x, &s0, &c0); sincosf(v.y, &s1, &c1);
    sincosf(v.z, &s2, &c2); sincosf(v.w, &s3, &c3);
    const int Ls = h * M_TOT + (j >> 3) * 128 + bs * 8 + (j & 7);  // j%4==0
    *reinterpret_cast<ushort2*>(R0 + Ls)     = make_ushort2(f2bf(s0), f2bf(s1));
    *reinterpret_cast<ushort2*>(R0 + Ls + 2) = make_ushort2(f2bf(s2), f2bf(s3));
    *reinterpret_cast<ushort2*>(R0 + Ls + 64)     = make_ushort2(f2bf(c0), f2bf(c1));
    *reinterpret_cast<ushort2*>(R0 + Ls + 64 + 2) = make_ushort2(f2bf(c2), f2bf(c3));
    if (blockIdx.x == 0) {
        if (threadIdx.x < 32) accum[threadIdx.x] = 0.0f;
        if (threadIdx.x == 32) *ticket = 0u;
    }
}

// ---------- fused step ----------
// grid = dim3(128, 2), block = 1024 (16 waves). Block (it, h): i in
// [it*16,+16) x 16 c-rows (8 sin + 8 cos of batches h*8..h*8+7).
// Wave w = k-sixteenth: 4 MFMAs; A = dense tiled loads (L2/L3-cached),
// B = Kb bf16 rows (L2/L3). MODE 0: convert K tile via LDS (+h==0 writes Kb).
// MODE 2: final wrap + fused coherence (ticket finalize).
template <int MODE>
__global__ __launch_bounds__(1024, 4) void step_kernel(
    const float* __restrict__ Kmat,
    unsigned short* __restrict__ Kb,
    const unsigned short* __restrict__ Rc,
    unsigned short* __restrict__ Rn,
    const float* __restrict__ omega,
    const float* __restrict__ kg,
    const float* __restrict__ mod,
    float* __restrict__ th,
    float* __restrict__ coh,
    float* __restrict__ accum,
    unsigned int* __restrict__ ticket)
{
    __shared__ float part[16][64][4];     // 16 KB
    __shared__ float coup[16][16];        // 1 KB

    const int t = threadIdx.x;
    const int lane = t & 63;
    const int w = t >> 6;                  // k-sixteenth 0..15
    const int it = blockIdx.x;
    const int h = blockIdx.y;
    const int i0 = it * 16;
    const int rl = lane & 15;
    const int kcol = w * 128 + ((lane >> 4) << 3);

    // ---- prefetch update inputs (threads 0..127 own the 128 theta cells)
    float th_o = 0.0f, sin_i = 0.0f, cos_i = 0.0f, om_i = 0.0f;
    size_t o_upd = 0; int bs = 0, il = 0, Ls = 0;
    if (t < 128) {
        bs = t >> 4; il = t & 15;
        o_upd = (size_t)(h * 8 + bs) * NOSC + i0 + il;
        th_o = th[o_upd];
        om_i = omega[i0 + il];
        sincosf(th_o, &sin_i, &cos_i);     // sin/cos of current (unwrapped) theta
        Ls = h * M_TOT + ((i0 + il) >> 3) * 128 + bs * 8 + ((i0 + il) & 7);
    }
    const float scale = kg[0] * (1.0f + mod[0]) * (1.0f / (float)NOSC);

    // ---- B fragments
    bf16x8 afr[4], bfr[4];
    if constexpr (MODE == 0) {
        __shared__ unsigned short Kt[16][KTP];     // 64.25 KB (step 0 only)
        const float4* __restrict__ src =
            reinterpret_cast<const float4*>(Kmat + (size_t)i0 * NOSC);
#pragma unroll
        for (int p = 0; p < 8; ++p) {
            const int q = t + p * 1024;            // float4 index 0..8191
            float4 v = src[q];
            ushort4 u = {f2bf(v.x), f2bf(v.y), f2bf(v.z), f2bf(v.w)};
            const int row = q >> 9;
            const int col = (q & 511) * 4;
            *reinterpret_cast<ushort4*>(&Kt[row][col]) = u;
            if (h == 0)
                *reinterpret_cast<ushort4*>(Kb + (size_t)(i0 + row) * NOSC + col) = u;
        }
        __syncthreads();
#pragma unroll
        for (int k = 0; k < 4; ++k)
            bfr[k] = *reinterpret_cast<const bf16x8*>(&Kt[rl][kcol + k * 32]);
    } else {
        const unsigned short* __restrict__ pbg =
            Kb + (size_t)(i0 + rl) * NOSC + kcol;
#pragma unroll
        for (int k = 0; k < 4; ++k)
            bfr[k] = *reinterpret_cast<const bf16x8*>(pbg + k * 32);
    }

    // ---- A fragments: dense tiled loads (plain -> L2/L3 cached)
    const unsigned short* __restrict__ pa =
        Rc + h * M_TOT + (w << 11) + (lane << 3);
#pragma unroll
    for (int k = 0; k < 4; ++k)
        afr[k] = *reinterpret_cast<const bf16x8*>(pa + (k << 9));

    f32x4 acc = {0.0f, 0.0f, 0.0f, 0.0f};
#pragma unroll
    for (int k = 0; k < 4; ++k)
        acc = __builtin_amdgcn_mfma_f32_16x16x32_bf16(afr[k], bfr[k], acc, 0, 0, 0);

    *reinterpret_cast<f32x4*>(&part[w][lane][0]) = acc;
    __syncthreads();

    // ---- reduce 16 k-partials: D row c16=(ln>>4)*4+rg, col il
    if (t < 256) {
        const int c16 = t >> 4, il2 = t & 15;
        const int ln = ((c16 >> 2) << 4) | il2, rg = c16 & 3;
        float s = 0.0f;
#pragma unroll
        for (int q = 0; q < 16; ++q) s += part[q][ln][rg];
        coup[c16][il2] = s;
    }
    __syncthreads();

    // ---- theta update for this block's 128 (b, i)
    if (t < 128) {
        const float aS = coup[bs][il];         // sin-dot rows 0..7
        const float aC = coup[8 + bs][il];     // cos-dot rows 8..15
        float nt = th_o + DT * (om_i + scale * (cos_i * aS - sin_i * aC));
        float ws, wc;
        sincosf(nt, &ws, &wc);
        if constexpr (MODE == 2) {
            th[o_upd] = atan2f(ws, wc);        // final wrap to (-pi, pi]
            // fused coherence: reduce over il (16-lane groups), 16 atomics/block
#pragma unroll
            for (int m = 1; m < 16; m <<= 1) {
                ws += __shfl_xor(ws, m);
                wc += __shfl_xor(wc, m);
            }
            if (il == 0) {
                atomicAdd(&accum[h * 8 + bs], ws);
                atomicAdd(&accum[16 + h * 8 + bs], wc);
            }
        } else {
            // wrap only shifts by 2*pi*k -> sin/cos unchanged; defer atan2
            th[o_upd] = nt;
            float sn = __shfl_down(ws, 1), cn = __shfl_down(wc, 1);
            if ((il & 1) == 0) {
                *reinterpret_cast<ushort2*>(Rn + Ls) = make_ushort2(f2bf(ws), f2bf(sn));
                *reinterpret_cast<ushort2*>(Rn + Ls + 64) = make_ushort2(f2bf(wc), f2bf(cn));
            }
        }
    }

    if constexpr (MODE == 2) {
        __syncthreads();
        __threadfence();
        if (t == 0) {
            const unsigned int tk = atomicAdd(ticket, 1u);
            if (tk == 255u) {                  // last block finalizes
                for (int b = 0; b < NB; ++b) {
                    float ss = atomicAdd(&accum[b], 0.0f) * (1.0f / (float)NOSC);
                    float cc = atomicAdd(&accum[16 + b], 0.0f) * (1.0f / (float)NOSC);
                    coh[b] = sqrtf(ss * ss + cc * cc);
                }
            }
        }
    }
}

extern "C" void kernel_launch(void* const* d_in, const int* in_sizes, int n_in,
                              void* d_out, int out_size, void* d_ws, size_t ws_size,
                              hipStream_t stream) {
    const float* theta_in = (const float*)d_in[0];
    const float* Kmat     = (const float*)d_in[1];
    const float* omega    = (const float*)d_in[2];
    const float* kg       = (const float*)d_in[3];
    const float* mod      = (const float*)d_in[4];

    float* th  = (float*)d_out;               // [NB][NOSC] final theta
    float* coh = (float*)d_out + M_TOT;       // [NB]

    unsigned short* Kb = (unsigned short*)d_ws;                       // 8 MB
    unsigned short* RA = Kb + (size_t)NOSC * NOSC;                    // 128 KB
    unsigned short* RB = RA + 2 * M_TOT;                              // 128 KB
    float* accum = (float*)(RB + 2 * M_TOT);                          // 32 f32
    unsigned int* ticket = (unsigned int*)(accum + 32);

    const dim3 grid(NOSC / 16, 2);            // 256 blocks, full GPU

    init_kernel<<<32, 256, 0, stream>>>(theta_in, th, RA, accum, ticket);

    // step 0: K convert (LDS staging; h==0 writes Kb), reads RA writes RB
    step_kernel<0><<<grid, 1024, 0, stream>>>(
        Kmat, Kb, RA, RB, omega, kg, mod, th, coh, accum, ticket);

    // steps 1..8: s odd reads RB writes RA, s even reads RA writes RB
    for (int s = 1; s < 9; ++s) {
        const unsigned short* rc = (s & 1) ? RB : RA;
        unsigned short* rn = (s & 1) ? RA : RB;
        step_kernel<1><<<grid, 1024, 0, stream>>>(
            Kmat, Kb, rc, rn, omega, kg, mod, th, coh, accum, ticket);
    }

    // step 9: reads RB; final wrap + fused coherence (no Rn write)
    step_kernel<2><<<grid, 1024, 0, stream>>>(
        Kmat, Kb, RB, RA, omega, kg, mod, th, coh, accum, ticket);
}

// Round 19
// 58.097 us; speedup vs baseline: 2.2808x; 2.2808x over previous
//
#include <hip/hip_runtime.h>
#include <math.h>

#define NOSC 2048
#define NB 16
#define DT 0.1f
#define M_TOT (NB * NOSC)    // 32768
#define KTP 2056             // padded LDS K row

typedef __attribute__((ext_vector_type(8))) short bf16x8;
typedef __attribute__((ext_vector_type(4))) float f32x4;

__device__ __forceinline__ unsigned short f2bf(float x) {
    unsigned int u = __float_as_uint(x);
    u += 0x7FFFu + ((u >> 16) & 1u);          // round-to-nearest-even
    return (unsigned short)(u >> 16);
}
__device__ __forceinline__ float bf2f(unsigned short u) {
    return __uint_as_float(((unsigned int)u) << 16);
}

// Fragment-tiled R (verified r15): sin idx(c,j) = (j>>3)*128 + c*8 + (j&7),
// cos at +M_TOT. Wave w's A-fragment chunk k is CONTIGUOUS at
// [w*2048 + k*512 + lane*8 .. +8) shorts.
__device__ __forceinline__ int ridx(int c, int j) {
    return ((j >> 3) << 7) + (c << 3) + (j & 7);
}

// Fragment-tiled K: Kbt offset(bx, w, k, lane) = (((bx*16+w)*4+k)<<9)+(lane<<3).
// Stored once in step 0 from the LDS tile; steps 1-9 read dense 1 KB/wave.

// ws layout: Kbt[8 MB] | RA (2*M_TOT shorts = 128 KB) | RB (128 KB)

// ---------- init: copy theta, build tiled R0 ----------
__global__ void init_kernel(const float* __restrict__ th_in,
                            float* __restrict__ th,
                            unsigned short* __restrict__ R0) {
    const int idx = blockIdx.x * 256 + threadIdx.x;   // 0..8191
    const int o4 = idx * 4;
    float4 v = *reinterpret_cast<const float4*>(th_in + o4);
    *reinterpret_cast<float4*>(th + o4) = v;
    const int b = o4 >> 11;
    const int j = o4 & (NOSC - 1);                    // j % 4 == 0
    float s0, c0, s1, c1, s2, c2, s3, c3;
    sincosf(v.x, &s0, &c0); sincosf(v.y, &s1, &c1);
    sincosf(v.z, &s2, &c2); sincosf(v.w, &s3, &c3);
    const int L = ridx(b, j);                         // 4 elems stay in-block
    ushort4 us = {f2bf(s0), f2bf(s1), f2bf(s2), f2bf(s3)};
    ushort4 uc = {f2bf(c0), f2bf(c1), f2bf(c2), f2bf(c3)};
    *reinterpret_cast<ushort4*>(R0 + L) = us;
    *reinterpret_cast<ushort4*>(R0 + M_TOT + L) = uc;
}

// ---------- fused step (r11 structure + dense tiled operands) ----------
// 128 blocks x 1024 thr (16 waves). Block owns i in [bx*16, +16), all 16
// batches. Wave w = k-sixteenth: dual 4-deep MFMA chains (sin/cos A-halves
// share B). FIRST: K tile f32->bf16 via LDS; each wave writes its B
// fragments DENSELY to Kbt. Else: B = dense Kbt loads.
template <bool FIRST, bool FINAL>
__global__ __launch_bounds__(1024, 4) void step_kernel(
    const float* __restrict__ Kmat,
    unsigned short* __restrict__ Kbt,
    const unsigned short* __restrict__ Rc,
    unsigned short* __restrict__ Rn,
    const float* __restrict__ omega,
    const float* __restrict__ kg,
    const float* __restrict__ mod,
    float* __restrict__ th)
{
    __shared__ float part[16][2][64][4];     // 32 KB
    __shared__ float coup[32][16];           // 2 KB

    const int t = threadIdx.x;
    const int lane = t & 63;
    const int w = t >> 6;
    const int i0 = blockIdx.x * 16;
    const int rl = lane & 15;
    const int kbase = w * 128 + ((lane >> 4) << 3);

    // ---- prefetch theta-update inputs (waves 0..3)
    float th_o = 0.0f, sin_i = 0.0f, cos_i = 0.0f, om_i = 0.0f;
    size_t o_upd = 0; int Lr = 0;
    if (t < 256) {
        const int b2 = t >> 4;
        const int il = t & 15;
        o_upd = (size_t)b2 * NOSC + i0 + il;
        Lr = ridx(b2, i0 + il);
        th_o = th[o_upd];
        sin_i = bf2f(Rc[Lr]);
        cos_i = bf2f(Rc[M_TOT + Lr]);
        om_i = omega[i0 + il];
    }
    const float scale = kg[0] * (1.0f + mod[0]) * (1.0f / (float)NOSC);

    // ---- B fragments
    bf16x8 as[4], ac[4], bb[4];
    unsigned short* __restrict__ kf =
        Kbt + (((size_t)blockIdx.x * 16 + w) << 11) + (lane << 3);
    if constexpr (FIRST) {
        __shared__ unsigned short Kt[16][KTP];       // 64.25 KB (step 0 only)
        const float4* __restrict__ src =
            reinterpret_cast<const float4*>(Kmat + (size_t)i0 * NOSC);
#pragma unroll
        for (int p = 0; p < 8; ++p) {
            const int q = t + p * 1024;              // float4 index 0..8191
            float4 v = src[q];
            ushort4 u = {f2bf(v.x), f2bf(v.y), f2bf(v.z), f2bf(v.w)};
            *reinterpret_cast<ushort4*>(&Kt[q >> 9][(q & 511) * 4]) = u;
        }
        __syncthreads();
#pragma unroll
        for (int k = 0; k < 4; ++k) {
            bb[k] = *reinterpret_cast<const bf16x8*>(&Kt[rl][kbase + k * 32]);
            // write-through in fragment-tiled order (dense 1 KB/wave stores)
            *reinterpret_cast<bf16x8*>(kf + (k << 9)) = bb[k];
        }
    } else {
#pragma unroll
        for (int k = 0; k < 4; ++k)
            bb[k] = *reinterpret_cast<const bf16x8*>(kf + (k << 9));
    }

    // ---- A fragments: dense tiled loads (L2/L3-cached plain loads)
    const unsigned short* __restrict__ pa = Rc + (w << 11) + (lane << 3);
#pragma unroll
    for (int k = 0; k < 4; ++k) {
        as[k] = *reinterpret_cast<const bf16x8*>(pa + (k << 9));
        ac[k] = *reinterpret_cast<const bf16x8*>(pa + M_TOT + (k << 9));
    }

    f32x4 acc_s = {0.0f, 0.0f, 0.0f, 0.0f};
    f32x4 acc_c = {0.0f, 0.0f, 0.0f, 0.0f};
#pragma unroll
    for (int k = 0; k < 4; ++k) {
        acc_s = __builtin_amdgcn_mfma_f32_16x16x32_bf16(as[k], bb[k], acc_s, 0, 0, 0);
        acc_c = __builtin_amdgcn_mfma_f32_16x16x32_bf16(ac[k], bb[k], acc_c, 0, 0, 0);
    }
    *reinterpret_cast<f32x4*>(&part[w][0][lane][0]) = acc_s;
    *reinterpret_cast<f32x4*>(&part[w][1][lane][0]) = acc_c;
    __syncthreads();

    // ---- reduce 16 k-partials: cell (c, il), c = half*16 + (ln>>4)*4 + rg
    if (t < 512) {
        const int c = t >> 4, il = t & 15;
        const int half = c >> 4, cl = c & 15;
        const int ln = ((cl >> 2) << 4) | il, rg = cl & 3;
        float s = 0.0f;
#pragma unroll
        for (int q = 0; q < 16; ++q) s += part[q][half][ln][rg];
        coup[c][il] = s;
    }
    __syncthreads();

    // ---- theta update for this block's 256 (b, i)
    if (t < 256) {
        const int b2 = t >> 4;
        const int il = t & 15;
        const float aS = coup[b2][il];
        const float aC = coup[16 + b2][il];
        float nt = th_o + DT * (om_i + scale * (cos_i * aS - sin_i * aC));
        float ws, wc;
        sincosf(nt, &ws, &wc);
        // wrap only shifts by 2*pi*k -> sin/cos unchanged; defer atan2
        th[o_upd] = FINAL ? atan2f(ws, wc) : nt;
        float sn = __shfl_down(ws, 1), cn = __shfl_down(wc, 1);
        if ((il & 1) == 0) {
            *reinterpret_cast<unsigned int*>(Rn + Lr) =
                (unsigned)f2bf(ws) | ((unsigned)f2bf(sn) << 16);
            *reinterpret_cast<unsigned int*>(Rn + M_TOT + Lr) =
                (unsigned)f2bf(wc) | ((unsigned)f2bf(cn) << 16);
        }
    }
}

// ---------- coherence from final tiled R ----------
__global__ void coherence_kernel(const unsigned short* __restrict__ R,
                                 float* __restrict__ coh) {
    const int b = blockIdx.x;
    const int t = threadIdx.x;
    const int j0 = t * 8;                    // 256 threads x 8 = 2048
    const int L = ridx(b, j0);               // 8 contiguous shorts
    float ss = 0.0f, sc = 0.0f;
#pragma unroll
    for (int e = 0; e < 8; ++e) {
        ss += bf2f(R[L + e]);
        sc += bf2f(R[M_TOT + L + e]);
    }
    for (int off = 32; off > 0; off >>= 1) {
        ss += __shfl_down(ss, off);
        sc += __shfl_down(sc, off);
    }
    __shared__ float red[8];
    const int w = t >> 6;
    if ((t & 63) == 0) { red[w * 2] = sc; red[w * 2 + 1] = ss; }
    __syncthreads();
    if (t == 0) {
        float tc = 0.0f, ts = 0.0f;
        for (int k = 0; k < 4; ++k) { tc += red[k * 2]; ts += red[k * 2 + 1]; }
        tc /= (float)NOSC;
        ts /= (float)NOSC;
        coh[b] = sqrtf(tc * tc + ts * ts);
    }
}

extern "C" void kernel_launch(void* const* d_in, const int* in_sizes, int n_in,
                              void* d_out, int out_size, void* d_ws, size_t ws_size,
                              hipStream_t stream) {
    const float* theta_in = (const float*)d_in[0];
    const float* Kmat     = (const float*)d_in[1];
    const float* omega    = (const float*)d_in[2];
    const float* kg       = (const float*)d_in[3];
    const float* mod      = (const float*)d_in[4];

    float* th  = (float*)d_out;               // [NB][NOSC] final theta
    float* coh = (float*)d_out + M_TOT;       // [NB]

    unsigned short* Kbt = (unsigned short*)d_ws;                      // 8 MB
    unsigned short* RA  = Kbt + (size_t)NOSC * NOSC;                  // 128 KB
    unsigned short* RB  = RA + 2 * M_TOT;                             // 128 KB

    init_kernel<<<32, 256, 0, stream>>>(theta_in, th, RA);

    for (int s = 0; s < 10; ++s) {
        const unsigned short* rc = (s & 1) ? RB : RA;
        unsigned short* rn = (s & 1) ? RA : RB;
        if (s == 0)
            step_kernel<true, false><<<NOSC / 16, 1024, 0, stream>>>(
                Kmat, Kbt, rc, rn, omega, kg, mod, th);
        else if (s < 9)
            step_kernel<false, false><<<NOSC / 16, 1024, 0, stream>>>(
                Kmat, Kbt, rc, rn, omega, kg, mod, th);
        else
            step_kernel<false, true><<<NOSC / 16, 1024, 0, stream>>>(
                Kmat, Kbt, rc, rn, omega, kg, mod, th);
    }

    // after 10 steps the live buffer is RA (step 9 wrote RA)
    coherence_kernel<<<NB, 256, 0, stream>>>(RA, coh);
}